// Round 1
// 936.303 us; speedup vs baseline: 1.0231x; 1.0231x over previous
//
#include <hip/hip_runtime.h>
#include <hip/hip_bf16.h>
#include <stdint.h>

#define DM   1024
#define BATCH 4
#define SEQ  4096
#define MTOT (BATCH*SEQ)   // 16384

typedef __attribute__((ext_vector_type(8))) short bf16x8;
typedef __attribute__((ext_vector_type(4))) float f32x4;

// async global->LDS, 16B per lane; LDS dest = uniform base + lane*16
#define GLOAD_LDS16(gp, lp) __builtin_amdgcn_global_load_lds( \
    (const __attribute__((address_space(1))) unsigned int*)(gp), \
    (__attribute__((address_space(3))) unsigned int*)(lp), 16, 0, 0)

// f32 -> bf16 bits, round-to-nearest-even
__device__ __forceinline__ ushort f2bf(float f){
  uint u = __float_as_uint(f);
  u += 0x7FFFu + ((u >> 16) & 1u);
  return (ushort)(u >> 16);
}
__device__ __forceinline__ float bf2f(ushort b){ return __uint_as_float(((uint)b) << 16); }

__device__ __forceinline__ void split4(const float4 v, ushort4& h4, ushort4& l4){
  h4.x = f2bf(v.x); l4.x = f2bf(v.x - bf2f(h4.x));
  h4.y = f2bf(v.y); l4.y = f2bf(v.y - bf2f(h4.y));
  h4.z = f2bf(v.z); l4.z = f2bf(v.z - bf2f(h4.z));
  h4.w = f2bf(v.w); l4.w = f2bf(v.w - bf2f(h4.w));
}

// ---------------------------------------------------------------------------
// prep_w_split: elementwise split W1,W2 into bf16 hi/lo planes.
// ---------------------------------------------------------------------------
__global__ __launch_bounds__(256)
void prep_w_split(const float* __restrict__ w1, const float* __restrict__ w2,
                  ushort* __restrict__ w1h, ushort* __restrict__ w1l,
                  ushort* __restrict__ w2h, ushort* __restrict__ w2l){
  const float* w = blockIdx.y ? w2 : w1;
  ushort* oh = blockIdx.y ? w2h : w1h;
  ushort* ol = blockIdx.y ? w2l : w1l;
  size_t off = ((size_t)blockIdx.x * 256 + threadIdx.x) * 4;
  float4 v = *(const float4*)&w[off];
  ushort4 h4, l4; split4(v, h4, l4);
  *(ushort4*)&oh[off] = h4;
  *(ushort4*)&ol[off] = l4;
}

// ---------------------------------------------------------------------------
// prep_xy: X = hidden, Y = hidden + pre. Split to bf16 planes once.
// Fused: beta[row] = Y[row,:] . c2   (one block == one row of 1024 floats,
// so the dot is a free block reduction; replaces the betak kernel and its
// 64 MB re-read of Yh/Yl). c2 must be computed before this launch.
// ---------------------------------------------------------------------------
__global__ __launch_bounds__(256)
void prep_xy(const float* __restrict__ hidden, const float* __restrict__ pre,
             ushort* __restrict__ xh, ushort* __restrict__ xl,
             ushort* __restrict__ yh, ushort* __restrict__ yl,
             const float* __restrict__ c2, float* __restrict__ beta, int writeX){
  __shared__ float red[4];
  const int tid = threadIdx.x, lane = tid & 63, wid = tid >> 6;
  size_t off = ((size_t)blockIdx.x * 256 + tid) * 4;
  float4 h = *(const float4*)&hidden[off];
  float4 p = *(const float4*)&pre[off];
  float4 y = {h.x + p.x, h.y + p.y, h.z + p.z, h.w + p.w};
  ushort4 a, b;
  if (writeX){
    split4(h, a, b);
    *(ushort4*)&xh[off] = a;
    *(ushort4*)&xl[off] = b;
  }
  split4(y, a, b);
  *(ushort4*)&yh[off] = a;
  *(ushort4*)&yl[off] = b;

  // beta reduction: thread tid holds row cols tid*4..tid*4+3
  float4 c = *(const float4*)&c2[tid * 4];
  float s = y.x * c.x + y.y * c.y + y.z * c.z + y.w * c.w;
  #pragma unroll
  for (int o = 32; o > 0; o >>= 1) s += __shfl_xor(s, o, 64);
  if (lane == 0) red[wid] = s;
  __syncthreads();
  if (tid == 0) beta[blockIdx.x] = red[0] + red[1] + red[2] + red[3];
}

// ---------------------------------------------------------------------------
// c2k: c2 = W2 @ b1. One wave per row.
// ---------------------------------------------------------------------------
__global__ __launch_bounds__(256)
void c2k(const float* __restrict__ w2, const float* __restrict__ b1,
         float* __restrict__ c2){
  const int wid = threadIdx.x >> 6, lane = threadIdx.x & 63;
  const int row = blockIdx.x * 4 + wid;
  float s = 0.f;
  #pragma unroll
  for (int t = 0; t < 16; t++){
    int e = lane + 64 * t;
    s += w2[(size_t)row * DM + e] * b1[e];
  }
  #pragma unroll
  for (int o = 32; o > 0; o >>= 1) s += __shfl_xor(s, o, 64);
  if (lane == 0) c2[row] = s;
}

// ---------------------------------------------------------------------------
// Shared split-bf16 B^T main loop: acc += A(m0..+128) @ B(n0..+128)^T over
// K=1024, all 4 planes async-staged (one plane per wave, 8 insts each).
//
// T2 bank-conflict swizzle (both-sides, rule #21): LDS rows are 64B; the
// unswizzled ds_read_b128 pattern put 4 lanes of every 8-lane phase on the
// same 4-bank group (measured 3.4e7 SQ_LDS_BANK_CONFLICT). We XOR the 16B
// chunk index with (row>>1)&3:
//   - write side: global_load_lds dest stays LINEAR; the permutation is
//     applied to the per-lane GLOBAL source chunk ((lane&3)^((lane>>3)&3)),
//     invariant across the 8 t-sub-loads (t moves rows by 16 == 0 mod 4
//     after >>1).
//   - read side: chunk offset ((lane>>4)^((lane>>1)&3))*8, a per-thread
//     constant (row = wm+i*16+lr keeps (row>>1)&3 == (lane>>1)&3).
// Involution => slot content is the original chunk c; per-lane data unchanged.
// Lanes 0..7 of each phase now cover all 8 bank groups exactly once.
// ---------------------------------------------------------------------------
__device__ __forceinline__ void bt_mainloop(
    const ushort* __restrict__ Aph, const ushort* __restrict__ Apl,
    const ushort* __restrict__ Bph, const ushort* __restrict__ Bpl,
    int m0, int n0, f32x4 (&acc)[4][4]){
  __shared__ alignas(16) ushort Ah[128*32];
  __shared__ alignas(16) ushort Al[128*32];
  __shared__ alignas(16) ushort Bh[128*32];
  __shared__ alignas(16) ushort Bl[128*32];

  const int tid = threadIdx.x;
  const int lane = tid & 63, wid = tid >> 6;
  const int wm = (wid & 1) * 64, wn = (wid >> 1) * 64;
  const int lr = lane & 15;
  const int lks = (((lane >> 4) ^ ((lane >> 1) & 3)) << 3);  // swizzled chunk

  const ushort* plane = (wid == 0) ? Aph : (wid == 1) ? Apl : (wid == 2) ? Bph : Bpl;
  ushort* lds = (wid == 0) ? Ah : (wid == 1) ? Al : (wid == 2) ? Bh : Bl;
  const int r0 = (wid < 2) ? m0 : n0;
  // pre-swizzled global source chunk (LDS dest stays linear: lane*16B)
  const size_t goff = (size_t)(r0 + (lane >> 2)) * DM
                    + (size_t)(((lane & 3) ^ ((lane >> 3) & 3)) * 8);

  for (int k0 = 0; k0 < DM; k0 += 32){
    __syncthreads();
    const ushort* gp = plane + goff + k0;
    #pragma unroll
    for (int t = 0; t < 8; t++){
      GLOAD_LDS16(gp + (size_t)t * 16 * DM, lds + t * 512);
    }
    __syncthreads();

    bf16x8 fah[4], fal[4], fbh[4], fbl[4];
    #pragma unroll
    for (int i = 0; i < 4; i++){
      fah[i] = *(const bf16x8*)&Ah[(wm + i*16 + lr)*32 + lks];
      fal[i] = *(const bf16x8*)&Al[(wm + i*16 + lr)*32 + lks];
      fbh[i] = *(const bf16x8*)&Bh[(wn + i*16 + lr)*32 + lks];
      fbl[i] = *(const bf16x8*)&Bl[(wn + i*16 + lr)*32 + lks];
    }
    #pragma unroll
    for (int i = 0; i < 4; i++)
      #pragma unroll
      for (int j = 0; j < 4; j++){
        acc[i][j] = __builtin_amdgcn_mfma_f32_16x16x32_bf16(fah[i], fbh[j], acc[i][j], 0, 0, 0);
        acc[i][j] = __builtin_amdgcn_mfma_f32_16x16x32_bf16(fah[i], fbl[j], acc[i][j], 0, 0, 0);
        acc[i][j] = __builtin_amdgcn_mfma_f32_16x16x32_bf16(fal[i], fbh[j], acc[i][j], 0, 0, 0);
      }
  }
}

// gemm_bt_split: out planes = split(A @ B^T). Used for Gt (8x8) and Z (8x128).
__global__ __launch_bounds__(256, 2)
void gemm_bt_split(const ushort* __restrict__ Aph, const ushort* __restrict__ Apl,
                   const ushort* __restrict__ Bph, const ushort* __restrict__ Bpl,
                   ushort* __restrict__ oh, ushort* __restrict__ ol){
  const int m0 = blockIdx.y * 128, n0 = blockIdx.x * 128;
  f32x4 acc[4][4];
  for (int i = 0; i < 4; i++) for (int j = 0; j < 4; j++) acc[i][j] = (f32x4){0.f,0.f,0.f,0.f};
  bt_mainloop(Aph, Apl, Bph, Bpl, m0, n0, acc);

  const int lane = threadIdx.x & 63, wid = threadIdx.x >> 6;
  const int wm = (wid & 1) * 64, wn = (wid >> 1) * 64;
  const int lr = lane & 15;
  const int rbase = (lane >> 4) * 4;
  #pragma unroll
  for (int i = 0; i < 4; i++)
    #pragma unroll
    for (int j = 0; j < 4; j++){
      int gc = n0 + wn + j*16 + lr;
      #pragma unroll
      for (int r = 0; r < 4; r++){
        int gr = m0 + wm + i*16 + rbase + r;
        float v = acc[i][j][r];
        ushort hb = f2bf(v);
        size_t o = (size_t)gr * DM + gc;
        oh[o] = hb;
        ol[o] = f2bf(v - bf2f(hb));
      }
    }
}

// gemm_bt_f32: out[b,q,k] = Z[b,q,:] . Y[b,k,:]  (raw logits, f32)
// grid (1024, BATCH). XCD-swizzled: each XCD's 64 resident blocks form an
// 8x8 (q,k) square (8 MB working set, L3-covered). NT stores keep Z/Y in L3.
__global__ __launch_bounds__(256, 2)
void gemm_bt_f32(const ushort* __restrict__ Aph, const ushort* __restrict__ Apl,
                 const ushort* __restrict__ Bph, const ushort* __restrict__ Bpl,
                 float* __restrict__ out){
  const int b = blockIdx.y;
  const int id = blockIdx.x;
  const int c = id & 7;              // XCD residue (dispatch round-robin)
  const int m = (id >> 3) & 63;      // 64 blocks per XCD per 512-group
  const int s = m >> 3, u = m & 7;
  const int g = id >> 9;             // 512-block group
  const int qt = 16*g + 8*(c & 1) + s;
  const int kt = 8*(c >> 1) + u;
  const int m0 = qt * 128, n0 = kt * 128;
  const size_t abase = (size_t)b * SEQ * DM;

  f32x4 acc[4][4];
  for (int i = 0; i < 4; i++) for (int j = 0; j < 4; j++) acc[i][j] = (f32x4){0.f,0.f,0.f,0.f};
  bt_mainloop(Aph + abase, Apl + abase, Bph + abase, Bpl + abase, m0, n0, acc);

  const int lane = threadIdx.x & 63, wid = threadIdx.x >> 6;
  const int wm = (wid & 1) * 64, wn = (wid >> 1) * 64;
  const int lr = lane & 15;
  const int rbase = (lane >> 4) * 4;
  #pragma unroll
  for (int i = 0; i < 4; i++)
    #pragma unroll
    for (int j = 0; j < 4; j++){
      int gc = n0 + wn + j*16 + lr;
      #pragma unroll
      for (int r = 0; r < 4; r++){
        int gr = m0 + wm + i*16 + rbase + r;
        __builtin_nontemporal_store(acc[i][j][r],
            &out[((size_t)b * SEQ + gr) * SEQ + gc]);
      }
    }
}

// ---------------------------------------------------------------------------
// gemm_z_manual (compact-ws fallback): Z = split(hidden @ Gt^T), A staged
// manually from f32 (split in VALU), B async. grid (8,128).
// B side gets the same T2 swizzle as bt_mainloop; A side already
// conflict-free via the ASTR=40 pad (row stride 20 dwords spreads banks).
// ---------------------------------------------------------------------------
#define ASTR 40
__global__ __launch_bounds__(256, 2)
void gemm_z_manual(const float* __restrict__ hidden,
                   const ushort* __restrict__ gth, const ushort* __restrict__ gtl,
                   ushort* __restrict__ zh, ushort* __restrict__ zl){
  const int m0 = blockIdx.y * 128, n0 = blockIdx.x * 128;
  __shared__ alignas(16) ushort Ah[128*ASTR];
  __shared__ alignas(16) ushort Al[128*ASTR];
  __shared__ alignas(16) ushort Bh[128*32];
  __shared__ alignas(16) ushort Bl[128*32];

  const int tid = threadIdx.x;
  const int lane = tid & 63, wid = tid >> 6;
  const int wm = (wid & 1) * 64, wn = (wid >> 1) * 64;
  const int lr = lane & 15, lk = (lane >> 4) * 8;
  const int lks = (((lane >> 4) ^ ((lane >> 1) & 3)) << 3);  // B-side swizzled chunk

  const ushort* bp = (wid < 2) ? gth : gtl;
  ushort* blds = (wid < 2) ? Bh : Bl;
  const int tb = (wid & 1) * 4;
  const size_t bgoff = (size_t)(n0 + (lane >> 2)) * DM
                     + (size_t)(((lane & 3) ^ ((lane >> 3) & 3)) * 8);

  f32x4 acc[4][4];
  for (int i = 0; i < 4; i++) for (int j = 0; j < 4; j++) acc[i][j] = (f32x4){0.f,0.f,0.f,0.f};

  for (int k0 = 0; k0 < DM; k0 += 32){
    __syncthreads();
    const ushort* gb = bp + bgoff + k0;
    #pragma unroll
    for (int t = 0; t < 4; t++){
      GLOAD_LDS16(gb + (size_t)(tb + t) * 16 * DM, blds + (tb + t) * 512);
    }
    #pragma unroll
    for (int c = 0; c < 4; c++){
      int idx = c * 256 + tid;
      int row = idx >> 3, kq = (idx & 7) * 4;
      size_t ga = (size_t)(m0 + row) * DM + k0 + kq;
      float4 v = *(const float4*)&hidden[ga];
      ushort4 h4, l4;
      split4(v, h4, l4);
      *(ushort4*)&Ah[row*ASTR + kq] = h4;
      *(ushort4*)&Al[row*ASTR + kq] = l4;
    }
    __syncthreads();

    bf16x8 fah[4], fal[4], fbh[4], fbl[4];
    #pragma unroll
    for (int i = 0; i < 4; i++){
      fah[i] = *(const bf16x8*)&Ah[(wm + i*16 + lr)*ASTR + lk];
      fal[i] = *(const bf16x8*)&Al[(wm + i*16 + lr)*ASTR + lk];
      fbh[i] = *(const bf16x8*)&Bh[(wn + i*16 + lr)*32 + lks];
      fbl[i] = *(const bf16x8*)&Bl[(wn + i*16 + lr)*32 + lks];
    }
    #pragma unroll
    for (int i = 0; i < 4; i++)
      #pragma unroll
      for (int j = 0; j < 4; j++){
        acc[i][j] = __builtin_amdgcn_mfma_f32_16x16x32_bf16(fah[i], fbh[j], acc[i][j], 0, 0, 0);
        acc[i][j] = __builtin_amdgcn_mfma_f32_16x16x32_bf16(fah[i], fbl[j], acc[i][j], 0, 0, 0);
        acc[i][j] = __builtin_amdgcn_mfma_f32_16x16x32_bf16(fal[i], fbh[j], acc[i][j], 0, 0, 0);
      }
  }

  const int rbase = (lane >> 4) * 4;
  #pragma unroll
  for (int i = 0; i < 4; i++)
    #pragma unroll
    for (int j = 0; j < 4; j++){
      int gc = n0 + wn + j*16 + lr;
      #pragma unroll
      for (int r = 0; r < 4; r++){
        int gr = m0 + wm + i*16 + rbase + r;
        float v = acc[i][j][r];
        ushort hb = f2bf(v);
        size_t o = (size_t)gr * DM + gc;
        zh[o] = hb;
        zl[o] = f2bf(v - bf2f(hb));
      }
    }
}

// ---------------------------------------------------------------------------
// softmax_rows: in-place row softmax over last dim (4096), + beta[k] column
// bias pre-add. Non-temporal in/out via native ext-vector f32x4.
// ---------------------------------------------------------------------------
__global__ __launch_bounds__(256)
void softmax_rows(float* __restrict__ out, const float* __restrict__ beta){
  __shared__ float red[8];
  const size_t row = blockIdx.x;
  float* p = out + row * (size_t)SEQ;
  const float* bp = beta + ((row >> 12) << 12);
  const int tid = threadIdx.x, lane = tid & 63, wid = tid >> 6;

  f32x4 v[4];
  float m = -3.0e38f;
  #pragma unroll
  for (int c = 0; c < 4; c++){
    v[c] = __builtin_nontemporal_load(((const f32x4*)p) + c*256 + tid);
    f32x4 bb = *(((const f32x4*)bp) + c*256 + tid);
    v[c] += bb;
    m = fmaxf(m, fmaxf(fmaxf(v[c].x, v[c].y), fmaxf(v[c].z, v[c].w)));
  }
  #pragma unroll
  for (int o = 32; o > 0; o >>= 1) m = fmaxf(m, __shfl_xor(m, o, 64));
  if (lane == 0) red[wid] = m;
  __syncthreads();
  const float M = fmaxf(fmaxf(red[0], red[1]), fmaxf(red[2], red[3]));

  float s = 0.f;
  #pragma unroll
  for (int c = 0; c < 4; c++){
    v[c].x = __expf(v[c].x - M); s += v[c].x;
    v[c].y = __expf(v[c].y - M); s += v[c].y;
    v[c].z = __expf(v[c].z - M); s += v[c].z;
    v[c].w = __expf(v[c].w - M); s += v[c].w;
  }
  #pragma unroll
  for (int o = 32; o > 0; o >>= 1) s += __shfl_xor(s, o, 64);
  if (lane == 0) red[4 + wid] = s;
  __syncthreads();
  const float inv = 1.0f / (red[4] + red[5] + red[6] + red[7]);
  #pragma unroll
  for (int c = 0; c < 4; c++){
    v[c] *= inv;
    __builtin_nontemporal_store(v[c], ((f32x4*)p) + c*256 + tid);
  }
}

// ---------------------------------------------------------------------------
extern "C" void kernel_launch(void* const* d_in, const int* in_sizes, int n_in,
                              void* d_out, int out_size, void* d_ws, size_t ws_size,
                              hipStream_t stream){
  const float* hidden = (const float*)d_in[0];
  const float* pre    = (const float*)d_in[1];
  const float* w1     = (const float*)d_in[2];
  const float* b1     = (const float*)d_in[3];
  const float* w2     = (const float*)d_in[4];
  // b2 unused: its contribution is constant per softmax row and cancels.
  float* out = (float*)d_out;

  char* ws = (char*)d_ws;
  const size_t WP = (size_t)DM * DM * sizeof(ushort);     // 2 MiB
  const size_t AP = (size_t)MTOT * DM * sizeof(ushort);   // 32 MiB
  const bool big = ws_size >= 6*AP + 6*WP + (1u << 20);

  ushort *w1h, *w1l, *w2h, *w2l, *Gth, *Gtl, *Xh, *Xl, *Yh, *Yl, *Zh, *Zl;
  float *c2, *beta;
  if (big){
    Xh  = (ushort*)(ws + 0*AP);  Xl  = (ushort*)(ws + 1*AP);
    Yh  = (ushort*)(ws + 2*AP);  Yl  = (ushort*)(ws + 3*AP);
    Zh  = (ushort*)(ws + 4*AP);  Zl  = (ushort*)(ws + 5*AP);
    w1h = (ushort*)(ws + 6*AP);          w1l = (ushort*)(ws + 6*AP + WP);
    w2h = (ushort*)(ws + 6*AP + 2*WP);   w2l = (ushort*)(ws + 6*AP + 3*WP);
    Gth = (ushort*)(ws + 6*AP + 4*WP);   Gtl = (ushort*)(ws + 6*AP + 5*WP);
    c2   = (float*)(ws + 6*AP + 6*WP);
    beta = c2 + DM;
  } else {
    Zh  = (ushort*)(ws + 0*AP);  Zl  = (ushort*)(ws + 1*AP);
    Yh  = (ushort*)(ws + 2*AP);  Yl  = (ushort*)(ws + 3*AP);
    Gth = (ushort*)(ws + 4*AP);  Gtl = (ushort*)(ws + 4*AP + WP);
    w1h = (ushort*)(ws + 0);       w1l = (ushort*)(ws + WP);
    w2h = (ushort*)(ws + 2*WP);    w2l = (ushort*)(ws + 3*WP);
    c2   = (float*)(ws + 4*AP + 2*WP);
    beta = c2 + DM;
    Xh = Xl = nullptr;
  }

  prep_w_split<<<dim3(1024, 2), 256, 0, stream>>>(w1, w2, w1h, w1l, w2h, w2l);
  c2k<<<dim3(256), 256, 0, stream>>>(w2, b1, c2);            // before prep_xy (beta fusion)
  prep_xy<<<dim3(16384), 256, 0, stream>>>(hidden, pre, Xh, Xl, Yh, Yl, c2, beta, big ? 1 : 0);
  // Gt = W2 @ W1^T  (so Z = X @ Gt^T = X @ W1 @ W2^T)
  gemm_bt_split<<<dim3(8, 8), 256, 0, stream>>>(w2h, w2l, w1h, w1l, Gth, Gtl);
  if (big){
    gemm_bt_split<<<dim3(8, 128), 256, 0, stream>>>(Xh, Xl, Gth, Gtl, Zh, Zl);
  } else {
    gemm_z_manual<<<dim3(8, 128), 256, 0, stream>>>(hidden, Gth, Gtl, Zh, Zl);
  }
  gemm_bt_f32<<<dim3(1024, BATCH), 256, 0, stream>>>(Zh, Zl, Yh, Yl, out);
  softmax_rows<<<dim3(MTOT), 256, 0, stream>>>(out, beta);
}

// Round 2
// 866.458 us; speedup vs baseline: 1.1056x; 1.0806x over previous
//
#include <hip/hip_runtime.h>
#include <hip/hip_bf16.h>
#include <stdint.h>

#define DM   1024
#define BATCH 4
#define SEQ  4096
#define MTOT (BATCH*SEQ)   // 16384

typedef __attribute__((ext_vector_type(8))) short bf16x8;
typedef __attribute__((ext_vector_type(4))) float f32x4;

// async global->LDS, 16B per lane; LDS dest = uniform base + lane*16
#define GLOAD_LDS16(gp, lp) __builtin_amdgcn_global_load_lds( \
    (const __attribute__((address_space(1))) unsigned int*)(gp), \
    (__attribute__((address_space(3))) unsigned int*)(lp), 16, 0, 0)

#define VMCNT(n) asm volatile("s_waitcnt vmcnt(" #n ")" ::: "memory")
#define BAR()    __builtin_amdgcn_s_barrier()
#define FENCE()  asm volatile("" ::: "memory")

// f32 -> bf16 bits, round-to-nearest-even
__device__ __forceinline__ ushort f2bf(float f){
  uint u = __float_as_uint(f);
  u += 0x7FFFu + ((u >> 16) & 1u);
  return (ushort)(u >> 16);
}
__device__ __forceinline__ float bf2f(ushort b){ return __uint_as_float(((uint)b) << 16); }

__device__ __forceinline__ void split4(const float4 v, ushort4& h4, ushort4& l4){
  h4.x = f2bf(v.x); l4.x = f2bf(v.x - bf2f(h4.x));
  h4.y = f2bf(v.y); l4.y = f2bf(v.y - bf2f(h4.y));
  h4.z = f2bf(v.z); l4.z = f2bf(v.z - bf2f(h4.z));
  h4.w = f2bf(v.w); l4.w = f2bf(v.w - bf2f(h4.w));
}

// ---------------------------------------------------------------------------
// prep_w_split: elementwise split W1,W2 into bf16 hi/lo planes.
// ---------------------------------------------------------------------------
__global__ __launch_bounds__(256)
void prep_w_split(const float* __restrict__ w1, const float* __restrict__ w2,
                  ushort* __restrict__ w1h, ushort* __restrict__ w1l,
                  ushort* __restrict__ w2h, ushort* __restrict__ w2l){
  const float* w = blockIdx.y ? w2 : w1;
  ushort* oh = blockIdx.y ? w2h : w1h;
  ushort* ol = blockIdx.y ? w2l : w1l;
  size_t off = ((size_t)blockIdx.x * 256 + threadIdx.x) * 4;
  float4 v = *(const float4*)&w[off];
  ushort4 h4, l4; split4(v, h4, l4);
  *(ushort4*)&oh[off] = h4;
  *(ushort4*)&ol[off] = l4;
}

// ---------------------------------------------------------------------------
// prep_xy: X = hidden, Y = hidden + pre. Split to bf16 planes once.
// Fused: beta[row] = Y[row,:] . c2  (block == one row).
// ---------------------------------------------------------------------------
__global__ __launch_bounds__(256)
void prep_xy(const float* __restrict__ hidden, const float* __restrict__ pre,
             ushort* __restrict__ xh, ushort* __restrict__ xl,
             ushort* __restrict__ yh, ushort* __restrict__ yl,
             const float* __restrict__ c2, float* __restrict__ beta, int writeX){
  __shared__ float red[4];
  const int tid = threadIdx.x, lane = tid & 63, wid = tid >> 6;
  size_t off = ((size_t)blockIdx.x * 256 + tid) * 4;
  float4 h = *(const float4*)&hidden[off];
  float4 p = *(const float4*)&pre[off];
  float4 y = {h.x + p.x, h.y + p.y, h.z + p.z, h.w + p.w};
  ushort4 a, b;
  if (writeX){
    split4(h, a, b);
    *(ushort4*)&xh[off] = a;
    *(ushort4*)&xl[off] = b;
  }
  split4(y, a, b);
  *(ushort4*)&yh[off] = a;
  *(ushort4*)&yl[off] = b;

  float4 c = *(const float4*)&c2[tid * 4];
  float s = y.x * c.x + y.y * c.y + y.z * c.z + y.w * c.w;
  #pragma unroll
  for (int o = 32; o > 0; o >>= 1) s += __shfl_xor(s, o, 64);
  if (lane == 0) red[wid] = s;
  __syncthreads();
  if (tid == 0) beta[blockIdx.x] = red[0] + red[1] + red[2] + red[3];
}

// ---------------------------------------------------------------------------
// c2k: c2 = W2 @ b1. One wave per row.
// ---------------------------------------------------------------------------
__global__ __launch_bounds__(256)
void c2k(const float* __restrict__ w2, const float* __restrict__ b1,
         float* __restrict__ c2){
  const int wid = threadIdx.x >> 6, lane = threadIdx.x & 63;
  const int row = blockIdx.x * 4 + wid;
  float s = 0.f;
  #pragma unroll
  for (int t = 0; t < 16; t++){
    int e = lane + 64 * t;
    s += w2[(size_t)row * DM + e] * b1[e];
  }
  #pragma unroll
  for (int o = 32; o > 0; o >>= 1) s += __shfl_xor(s, o, 64);
  if (lane == 0) c2[row] = s;
}

// ===========================================================================
// 256x256 pipelined split-bf16 B^T mainloop (T2+T3+T4+T5 stack, m201-style).
//
// Geometry: 512 thr = 8 waves (2M x 4N), per-wave out 128x64, BK=32,
// LDS = 2 buf x 4 planes (Ah,Al,Bh,Bl) x [256][32] bf16 = 128 KiB, 1 blk/CU.
//
// Per K-tile: 4 phases = C-quadrants (qa,qb): 00 -> 01 -> 11 -> 10.
//   phase: vmcnt(gate); s_barrier; ds_read NEW frags only; issue next-tile
//          unit (2 x global_load_lds); setprio(1); 24 MFMA (3 passes hh/hl/lh,
//          dependency-spread); setprio(0); s_barrier.
// Frag reuse: A-set lives 2 phases, B0/B1 sets live the whole tile
//   -> 24 ds_read_b128 per tile (vs 48 naive) -> MFMA-bound.
// Unit issue order A0,B0,B1,A1 -> every steady-state gate is vmcnt(4)
//   (never 0 in the main loop; each unit has >=3 phases of flight time).
// T2 swizzle both-sides (rule #21): LDS linear dest, global source chunk
//   (lane&3)^((lane>>3)&3), read chunk (lane>>4)^((lane>>1)&3).
// ===========================================================================
__device__ __forceinline__ void mainloop256(
    const ushort* __restrict__ Aph, const ushort* __restrict__ Apl,
    const ushort* __restrict__ Bph, const ushort* __restrict__ Bpl,
    int m0, int n0, f32x4 (&acc)[8][4]){
  __shared__ alignas(16) ushort lds[2][4][256*32];

  const int tid = threadIdx.x;
  const int lane = tid & 63, wv = tid >> 6;
  const int wm = (wv & 1) * 128, wn = (wv >> 1) * 64;
  const int lr = lane & 15;
  const int lks = (((lane >> 4) ^ ((lane >> 1) & 3)) << 3);

  // staging geometry: one unit = 16 KiB = {H,L} planes x 128 rows x 64 B
  const int rowidx = tid >> 2;                         // 0..127
  const int srcc = (((tid & 3) ^ ((tid >> 3) & 3)) << 3);  // pre-swizzled chunk
  const int arow = rowidx + (rowidx & 64);             // + qa*64: rows {0-63,128-191}
  const int brow = ((rowidx >> 5) << 6) + (rowidx & 31);   // + qb*32: 4 stripes
  const int awrow = wv * 16 + ((wv & 4) << 4);         // wave-uniform dest rows
  const int bwrow = ((wv >> 1) << 6) + ((wv & 1) << 4);

  auto stageA = [&](int bf, int qa, int kt){
    const size_t g = (size_t)(m0 + qa * 64 + arow) * DM + kt * 32 + srcc;
    GLOAD_LDS16(Aph + g, &lds[bf][0][(qa * 64 + awrow) * 32]);
    GLOAD_LDS16(Apl + g, &lds[bf][1][(qa * 64 + awrow) * 32]);
  };
  auto stageB = [&](int bf, int qb, int kt){
    const size_t g = (size_t)(n0 + qb * 32 + brow) * DM + kt * 32 + srcc;
    GLOAD_LDS16(Bph + g, &lds[bf][2][(qb * 32 + bwrow) * 32]);
    GLOAD_LDS16(Bpl + g, &lds[bf][3][(qb * 32 + bwrow) * 32]);
  };

  bf16x8 ah[4], al[4], bh0[2], bl0[2], bh1[2], bl1[2];

#define DS_A(CUR, QA) do { _Pragma("unroll") for (int i = 0; i < 4; i++){ \
    ah[i] = *(const bf16x8*)&lds[CUR][0][(wm + (QA)*64 + i*16 + lr)*32 + lks]; \
    al[i] = *(const bf16x8*)&lds[CUR][1][(wm + (QA)*64 + i*16 + lr)*32 + lks]; } } while(0)
#define DS_B(CUR, QB, BH, BL) do { _Pragma("unroll") for (int j = 0; j < 2; j++){ \
    BH[j] = *(const bf16x8*)&lds[CUR][2][(wn + (QB)*32 + j*16 + lr)*32 + lks]; \
    BL[j] = *(const bf16x8*)&lds[CUR][3][(wn + (QB)*32 + j*16 + lr)*32 + lks]; } } while(0)
// 3 passes (hh, hl, lh): same-acc MFMAs are 8 apart (covers MFMA latency);
// per-element add order unchanged vs old code -> bit-identical results.
#define MFMA3(QA, QB, BH, BL) do { \
  __builtin_amdgcn_s_setprio(1); \
  _Pragma("unroll") for (int i = 0; i < 4; i++) _Pragma("unroll") for (int j = 0; j < 2; j++) \
    acc[(QA)*4+i][(QB)*2+j] = __builtin_amdgcn_mfma_f32_16x16x32_bf16(ah[i], BH[j], acc[(QA)*4+i][(QB)*2+j], 0, 0, 0); \
  _Pragma("unroll") for (int i = 0; i < 4; i++) _Pragma("unroll") for (int j = 0; j < 2; j++) \
    acc[(QA)*4+i][(QB)*2+j] = __builtin_amdgcn_mfma_f32_16x16x32_bf16(ah[i], BL[j], acc[(QA)*4+i][(QB)*2+j], 0, 0, 0); \
  _Pragma("unroll") for (int i = 0; i < 4; i++) _Pragma("unroll") for (int j = 0; j < 2; j++) \
    acc[(QA)*4+i][(QB)*2+j] = __builtin_amdgcn_mfma_f32_16x16x32_bf16(al[i], BH[j], acc[(QA)*4+i][(QB)*2+j], 0, 0, 0); \
  __builtin_amdgcn_s_setprio(0); } while(0)

  // prologue: tile 0 units in issue order A0,B0,B1,A1 (8 VMEM insts)
  stageA(0, 0, 0); stageB(0, 0, 0); stageB(0, 1, 0); stageA(0, 1, 0);

  for (int t = 0; t < 31; ++t){
    const int cur = t & 1, nxt = cur ^ 1;
    // ph0 (0,0): needs A0,B0 of tile t -> drain to 4 outstanding (B1,A1)
    VMCNT(4); BAR(); FENCE();
    DS_A(cur, 0); DS_B(cur, 0, bh0, bl0);
    stageA(nxt, 0, t + 1);
    MFMA3(0, 0, bh0, bl0);
    BAR();
    // ph1 (0,1): needs B1 -> leave A1(t),A0(t+1)
    VMCNT(4); BAR(); FENCE();
    DS_B(cur, 1, bh1, bl1);
    stageB(nxt, 0, t + 1);
    MFMA3(0, 1, bh1, bl1);
    BAR();
    // ph2 (1,1): needs A1 -> leave A0(t+1),B0(t+1)
    VMCNT(4); BAR(); FENCE();
    DS_A(cur, 1);
    stageB(nxt, 1, t + 1);
    MFMA3(1, 1, bh1, bl1);
    BAR();
    // ph3 (1,0): no new data (reuses A1-set + B0-set), no gate
    stageA(nxt, 1, t + 1);
    MFMA3(1, 0, bh0, bl0);
    BAR();
  }
  // final tile t=31 (cur=1), no staging; gates 4 -> 2 -> 0
  {
    VMCNT(4); BAR(); FENCE();
    DS_A(1, 0); DS_B(1, 0, bh0, bl0);
    MFMA3(0, 0, bh0, bl0);
    BAR();
    VMCNT(2); BAR(); FENCE();
    DS_B(1, 1, bh1, bl1);
    MFMA3(0, 1, bh1, bl1);
    BAR();
    VMCNT(0); BAR(); FENCE();
    DS_A(1, 1);
    MFMA3(1, 1, bh1, bl1);
    BAR();
    MFMA3(1, 0, bh0, bl0);
  }
#undef DS_A
#undef DS_B
#undef MFMA3
}

// gemm_bt_split256: out planes = split(A @ B^T), 256^2 tiles. Used for Z.
__global__ __launch_bounds__(512, 2)
void gemm_bt_split256(const ushort* __restrict__ Aph, const ushort* __restrict__ Apl,
                      const ushort* __restrict__ Bph, const ushort* __restrict__ Bpl,
                      ushort* __restrict__ oh, ushort* __restrict__ ol){
  const int m0 = blockIdx.y * 256, n0 = blockIdx.x * 256;
  f32x4 acc[8][4] = {};
  mainloop256(Aph, Apl, Bph, Bpl, m0, n0, acc);

  const int tid = threadIdx.x, lane = tid & 63, wv = tid >> 6;
  const int wm = (wv & 1) * 128, wn = (wv >> 1) * 64;
  const int lr = lane & 15, rbase = (lane >> 4) * 4;
  #pragma unroll
  for (int I = 0; I < 8; I++)
    #pragma unroll
    for (int J = 0; J < 4; J++){
      int gc = n0 + wn + J*16 + lr;
      #pragma unroll
      for (int r = 0; r < 4; r++){
        int gr = m0 + wm + I*16 + rbase + r;
        float v = acc[I][J][r];
        ushort hb = f2bf(v);
        size_t o = (size_t)gr * DM + gc;
        oh[o] = hb;
        ol[o] = f2bf(v - bf2f(hb));
      }
    }
}

// gemm_bt_f32_256: out[b,q,k] = Z[b,q,:] . Y[b,k,:] (raw logits, f32).
// grid (256, BATCH): 1 blk/CU, exactly 4 batch-aligned rounds. Bijective XCD
// swizzle: XCD c owns a 4x8 (q,k) tile region.
__global__ __launch_bounds__(512, 2)
void gemm_bt_f32_256(const ushort* __restrict__ Aph, const ushort* __restrict__ Apl,
                     const ushort* __restrict__ Bph, const ushort* __restrict__ Bpl,
                     float* __restrict__ out){
  const int b = blockIdx.y;
  const int id = blockIdx.x;          // 0..255
  const int c = id & 7;               // XCD residue
  const int m = id >> 3;              // 0..31
  const int qt = (c >> 1) * 4 + (m >> 3);   // 0..15
  const int kt = (c & 1) * 8 + (m & 7);     // 0..15
  const int m0 = qt * 256, n0 = kt * 256;
  const size_t abase = (size_t)b * SEQ * DM;

  f32x4 acc[8][4] = {};
  mainloop256(Aph + abase, Apl + abase, Bph + abase, Bpl + abase, m0, n0, acc);

  const int tid = threadIdx.x, lane = tid & 63, wv = tid >> 6;
  const int wm = (wv & 1) * 128, wn = (wv >> 1) * 64;
  const int lr = lane & 15, rbase = (lane >> 4) * 4;
  #pragma unroll
  for (int I = 0; I < 8; I++)
    #pragma unroll
    for (int J = 0; J < 4; J++){
      int gc = n0 + wn + J*16 + lr;
      #pragma unroll
      for (int r = 0; r < 4; r++){
        int gr = m0 + wm + I*16 + rbase + r;
        __builtin_nontemporal_store(acc[I][J][r],
            &out[((size_t)b * SEQ + gr) * SEQ + gc]);
      }
    }
}

// ---------------------------------------------------------------------------
// Old 128^2 2-phase mainloop — kept for the tiny Gt GEMM (needs 64 blocks
// for occupancy; 16 x 256^2 blocks would idle 94% of the chip).
// ---------------------------------------------------------------------------
__device__ __forceinline__ void bt_mainloop(
    const ushort* __restrict__ Aph, const ushort* __restrict__ Apl,
    const ushort* __restrict__ Bph, const ushort* __restrict__ Bpl,
    int m0, int n0, f32x4 (&acc)[4][4]){
  __shared__ alignas(16) ushort Ah[128*32];
  __shared__ alignas(16) ushort Al[128*32];
  __shared__ alignas(16) ushort Bh[128*32];
  __shared__ alignas(16) ushort Bl[128*32];

  const int tid = threadIdx.x;
  const int lane = tid & 63, wid = tid >> 6;
  const int wm = (wid & 1) * 64, wn = (wid >> 1) * 64;
  const int lr = lane & 15;
  const int lks = (((lane >> 4) ^ ((lane >> 1) & 3)) << 3);

  const ushort* plane = (wid == 0) ? Aph : (wid == 1) ? Apl : (wid == 2) ? Bph : Bpl;
  ushort* lds = (wid == 0) ? Ah : (wid == 1) ? Al : (wid == 2) ? Bh : Bl;
  const int r0 = (wid < 2) ? m0 : n0;
  const size_t goff = (size_t)(r0 + (lane >> 2)) * DM
                    + (size_t)(((lane & 3) ^ ((lane >> 3) & 3)) * 8);

  for (int k0 = 0; k0 < DM; k0 += 32){
    __syncthreads();
    const ushort* gp = plane + goff + k0;
    #pragma unroll
    for (int t = 0; t < 8; t++){
      GLOAD_LDS16(gp + (size_t)t * 16 * DM, lds + t * 512);
    }
    __syncthreads();

    bf16x8 fah[4], fal[4], fbh[4], fbl[4];
    #pragma unroll
    for (int i = 0; i < 4; i++){
      fah[i] = *(const bf16x8*)&Ah[(wm + i*16 + lr)*32 + lks];
      fal[i] = *(const bf16x8*)&Al[(wm + i*16 + lr)*32 + lks];
      fbh[i] = *(const bf16x8*)&Bh[(wn + i*16 + lr)*32 + lks];
      fbl[i] = *(const bf16x8*)&Bl[(wn + i*16 + lr)*32 + lks];
    }
    #pragma unroll
    for (int i = 0; i < 4; i++)
      #pragma unroll
      for (int j = 0; j < 4; j++){
        acc[i][j] = __builtin_amdgcn_mfma_f32_16x16x32_bf16(fah[i], fbh[j], acc[i][j], 0, 0, 0);
        acc[i][j] = __builtin_amdgcn_mfma_f32_16x16x32_bf16(fah[i], fbl[j], acc[i][j], 0, 0, 0);
        acc[i][j] = __builtin_amdgcn_mfma_f32_16x16x32_bf16(fal[i], fbh[j], acc[i][j], 0, 0, 0);
      }
  }
}

// gemm_bt_split: out planes = split(A @ B^T). Used for Gt (8x8).
__global__ __launch_bounds__(256, 2)
void gemm_bt_split(const ushort* __restrict__ Aph, const ushort* __restrict__ Apl,
                   const ushort* __restrict__ Bph, const ushort* __restrict__ Bpl,
                   ushort* __restrict__ oh, ushort* __restrict__ ol){
  const int m0 = blockIdx.y * 128, n0 = blockIdx.x * 128;
  f32x4 acc[4][4];
  for (int i = 0; i < 4; i++) for (int j = 0; j < 4; j++) acc[i][j] = (f32x4){0.f,0.f,0.f,0.f};
  bt_mainloop(Aph, Apl, Bph, Bpl, m0, n0, acc);

  const int lane = threadIdx.x & 63, wid = threadIdx.x >> 6;
  const int wm = (wid & 1) * 64, wn = (wid >> 1) * 64;
  const int lr = lane & 15;
  const int rbase = (lane >> 4) * 4;
  #pragma unroll
  for (int i = 0; i < 4; i++)
    #pragma unroll
    for (int j = 0; j < 4; j++){
      int gc = n0 + wn + j*16 + lr;
      #pragma unroll
      for (int r = 0; r < 4; r++){
        int gr = m0 + wm + i*16 + rbase + r;
        float v = acc[i][j][r];
        ushort hb = f2bf(v);
        size_t o = (size_t)gr * DM + gc;
        oh[o] = hb;
        ol[o] = f2bf(v - bf2f(hb));
      }
    }
}

// ---------------------------------------------------------------------------
// gemm_z_manual (compact-ws fallback): Z = split(hidden @ Gt^T), A staged
// manually from f32 (split in VALU), B async. grid (8,128).
// ---------------------------------------------------------------------------
#define ASTR 40
__global__ __launch_bounds__(256, 2)
void gemm_z_manual(const float* __restrict__ hidden,
                   const ushort* __restrict__ gth, const ushort* __restrict__ gtl,
                   ushort* __restrict__ zh, ushort* __restrict__ zl){
  const int m0 = blockIdx.y * 128, n0 = blockIdx.x * 128;
  __shared__ alignas(16) ushort Ah[128*ASTR];
  __shared__ alignas(16) ushort Al[128*ASTR];
  __shared__ alignas(16) ushort Bh[128*32];
  __shared__ alignas(16) ushort Bl[128*32];

  const int tid = threadIdx.x;
  const int lane = tid & 63, wid = tid >> 6;
  const int wm = (wid & 1) * 64, wn = (wid >> 1) * 64;
  const int lr = lane & 15, lk = (lane >> 4) * 8;
  const int lks = (((lane >> 4) ^ ((lane >> 1) & 3)) << 3);

  const ushort* bp = (wid < 2) ? gth : gtl;
  ushort* blds = (wid < 2) ? Bh : Bl;
  const int tb = (wid & 1) * 4;
  const size_t bgoff = (size_t)(n0 + (lane >> 2)) * DM
                     + (size_t)(((lane & 3) ^ ((lane >> 3) & 3)) * 8);

  f32x4 acc[4][4];
  for (int i = 0; i < 4; i++) for (int j = 0; j < 4; j++) acc[i][j] = (f32x4){0.f,0.f,0.f,0.f};

  for (int k0 = 0; k0 < DM; k0 += 32){
    __syncthreads();
    const ushort* gb = bp + bgoff + k0;
    #pragma unroll
    for (int t = 0; t < 4; t++){
      GLOAD_LDS16(gb + (size_t)(tb + t) * 16 * DM, blds + (tb + t) * 512);
    }
    #pragma unroll
    for (int c = 0; c < 4; c++){
      int idx = c * 256 + tid;
      int row = idx >> 3, kq = (idx & 7) * 4;
      size_t ga = (size_t)(m0 + row) * DM + k0 + kq;
      float4 v = *(const float4*)&hidden[ga];
      ushort4 h4, l4;
      split4(v, h4, l4);
      *(ushort4*)&Ah[row*ASTR + kq] = h4;
      *(ushort4*)&Al[row*ASTR + kq] = l4;
    }
    __syncthreads();

    bf16x8 fah[4], fal[4], fbh[4], fbl[4];
    #pragma unroll
    for (int i = 0; i < 4; i++){
      fah[i] = *(const bf16x8*)&Ah[(wm + i*16 + lr)*ASTR + lk];
      fal[i] = *(const bf16x8*)&Al[(wm + i*16 + lr)*ASTR + lk];
      fbh[i] = *(const bf16x8*)&Bh[(wn + i*16 + lr)*32 + lks];
      fbl[i] = *(const bf16x8*)&Bl[(wn + i*16 + lr)*32 + lks];
    }
    #pragma unroll
    for (int i = 0; i < 4; i++)
      #pragma unroll
      for (int j = 0; j < 4; j++){
        acc[i][j] = __builtin_amdgcn_mfma_f32_16x16x32_bf16(fah[i], fbh[j], acc[i][j], 0, 0, 0);
        acc[i][j] = __builtin_amdgcn_mfma_f32_16x16x32_bf16(fah[i], fbl[j], acc[i][j], 0, 0, 0);
        acc[i][j] = __builtin_amdgcn_mfma_f32_16x16x32_bf16(fal[i], fbh[j], acc[i][j], 0, 0, 0);
      }
  }

  const int rbase = (lane >> 4) * 4;
  #pragma unroll
  for (int i = 0; i < 4; i++)
    #pragma unroll
    for (int j = 0; j < 4; j++){
      int gc = n0 + wn + j*16 + lr;
      #pragma unroll
      for (int r = 0; r < 4; r++){
        int gr = m0 + wm + i*16 + rbase + r;
        float v = acc[i][j][r];
        ushort hb = f2bf(v);
        size_t o = (size_t)gr * DM + gc;
        zh[o] = hb;
        zl[o] = f2bf(v - bf2f(hb));
      }
    }
}

// ---------------------------------------------------------------------------
// softmax_rows: in-place row softmax over last dim (4096), + beta[k] column
// bias pre-add. Non-temporal in/out via native ext-vector f32x4.
// ---------------------------------------------------------------------------
__global__ __launch_bounds__(256)
void softmax_rows(float* __restrict__ out, const float* __restrict__ beta){
  __shared__ float red[8];
  const size_t row = blockIdx.x;
  float* p = out + row * (size_t)SEQ;
  const float* bp = beta + ((row >> 12) << 12);
  const int tid = threadIdx.x, lane = tid & 63, wid = tid >> 6;

  f32x4 v[4];
  float m = -3.0e38f;
  #pragma unroll
  for (int c = 0; c < 4; c++){
    v[c] = __builtin_nontemporal_load(((const f32x4*)p) + c*256 + tid);
    f32x4 bb = *(((const f32x4*)bp) + c*256 + tid);
    v[c] += bb;
    m = fmaxf(m, fmaxf(fmaxf(v[c].x, v[c].y), fmaxf(v[c].z, v[c].w)));
  }
  #pragma unroll
  for (int o = 32; o > 0; o >>= 1) m = fmaxf(m, __shfl_xor(m, o, 64));
  if (lane == 0) red[wid] = m;
  __syncthreads();
  const float M = fmaxf(fmaxf(red[0], red[1]), fmaxf(red[2], red[3]));

  float s = 0.f;
  #pragma unroll
  for (int c = 0; c < 4; c++){
    v[c].x = __expf(v[c].x - M); s += v[c].x;
    v[c].y = __expf(v[c].y - M); s += v[c].y;
    v[c].z = __expf(v[c].z - M); s += v[c].z;
    v[c].w = __expf(v[c].w - M); s += v[c].w;
  }
  #pragma unroll
  for (int o = 32; o > 0; o >>= 1) s += __shfl_xor(s, o, 64);
  if (lane == 0) red[4 + wid] = s;
  __syncthreads();
  const float inv = 1.0f / (red[4] + red[5] + red[6] + red[7]);
  #pragma unroll
  for (int c = 0; c < 4; c++){
    v[c] *= inv;
    __builtin_nontemporal_store(v[c], ((f32x4*)p) + c*256 + tid);
  }
}

// ---------------------------------------------------------------------------
extern "C" void kernel_launch(void* const* d_in, const int* in_sizes, int n_in,
                              void* d_out, int out_size, void* d_ws, size_t ws_size,
                              hipStream_t stream){
  const float* hidden = (const float*)d_in[0];
  const float* pre    = (const float*)d_in[1];
  const float* w1     = (const float*)d_in[2];
  const float* b1     = (const float*)d_in[3];
  const float* w2     = (const float*)d_in[4];
  // b2 unused: its contribution is constant per softmax row and cancels.
  float* out = (float*)d_out;

  char* ws = (char*)d_ws;
  const size_t WP = (size_t)DM * DM * sizeof(ushort);     // 2 MiB
  const size_t AP = (size_t)MTOT * DM * sizeof(ushort);   // 32 MiB
  const bool big = ws_size >= 6*AP + 6*WP + (1u << 20);

  ushort *w1h, *w1l, *w2h, *w2l, *Gth, *Gtl, *Xh, *Xl, *Yh, *Yl, *Zh, *Zl;
  float *c2, *beta;
  if (big){
    Xh  = (ushort*)(ws + 0*AP);  Xl  = (ushort*)(ws + 1*AP);
    Yh  = (ushort*)(ws + 2*AP);  Yl  = (ushort*)(ws + 3*AP);
    Zh  = (ushort*)(ws + 4*AP);  Zl  = (ushort*)(ws + 5*AP);
    w1h = (ushort*)(ws + 6*AP);          w1l = (ushort*)(ws + 6*AP + WP);
    w2h = (ushort*)(ws + 6*AP + 2*WP);   w2l = (ushort*)(ws + 6*AP + 3*WP);
    Gth = (ushort*)(ws + 6*AP + 4*WP);   Gtl = (ushort*)(ws + 6*AP + 5*WP);
    c2   = (float*)(ws + 6*AP + 6*WP);
    beta = c2 + DM;
  } else {
    Zh  = (ushort*)(ws + 0*AP);  Zl  = (ushort*)(ws + 1*AP);
    Yh  = (ushort*)(ws + 2*AP);  Yl  = (ushort*)(ws + 3*AP);
    Gth = (ushort*)(ws + 4*AP);  Gtl = (ushort*)(ws + 4*AP + WP);
    w1h = (ushort*)(ws + 0);       w1l = (ushort*)(ws + WP);
    w2h = (ushort*)(ws + 2*WP);    w2l = (ushort*)(ws + 3*WP);
    c2   = (float*)(ws + 4*AP + 2*WP);
    beta = c2 + DM;
    Xh = Xl = nullptr;
  }

  prep_w_split<<<dim3(1024, 2), 256, 0, stream>>>(w1, w2, w1h, w1l, w2h, w2l);
  c2k<<<dim3(256), 256, 0, stream>>>(w2, b1, c2);            // before prep_xy (beta fusion)
  prep_xy<<<dim3(16384), 256, 0, stream>>>(hidden, pre, Xh, Xl, Yh, Yl, c2, beta, big ? 1 : 0);
  // Gt = W2 @ W1^T  (so Z = X @ Gt^T = X @ W1 @ W2^T)
  gemm_bt_split<<<dim3(8, 8), 256, 0, stream>>>(w2h, w2l, w1h, w1l, Gth, Gtl);
  if (big){
    gemm_bt_split256<<<dim3(4, 64), 512, 0, stream>>>(Xh, Xl, Gth, Gtl, Zh, Zl);
  } else {
    gemm_z_manual<<<dim3(8, 128), 256, 0, stream>>>(hidden, Gth, Gtl, Zh, Zl);
  }
  gemm_bt_f32_256<<<dim3(256, BATCH), 512, 0, stream>>>(Zh, Zl, Yh, Yl, out);
  softmax_rows<<<dim3(MTOT), 256, 0, stream>>>(out, beta);
}